// Round 2
// baseline (406.756 us; speedup 1.0000x reference)
//
#include <hip/hip_runtime.h>
#include <hip/hip_bf16.h>

// Problem constants (reference: x [64,256,64,64] fp32, keep_num=2048)
#define BB 64
#define CC 256
#define NN 4096          // 64*64 tokens
#define KKEEP 2048
#define CCHUNK 64        // channel chunk per partial-score block (4 chunks)

// ---------------------------------------------------------------------------
// Kernel 1: partial token scores.  P[cy][b][n] = sum_{c in chunk cy} |x[b,c,n]|
// grid = (B*4, 4)  block = 256.  Each thread: 4 tokens (float4), 64 channels.
// 1024 blocks -> 4 blocks/CU -> 16 waves/CU; coalesced 1 KiB/wave/instr.
// ---------------------------------------------------------------------------
__global__ __launch_bounds__(256) void score_partial_kernel(
    const float* __restrict__ x, float* __restrict__ P) {
    const int b  = blockIdx.x >> 2;
    const int ng = blockIdx.x & 3;
    const int cy = blockIdx.y;
    const int n0 = ng * 1024 + threadIdx.x * 4;
    const float* xb = x + (size_t)(b * CC + cy * CCHUNK) * NN + n0;
    float4 acc = make_float4(0.f, 0.f, 0.f, 0.f);
    #pragma unroll 8
    for (int c = 0; c < CCHUNK; ++c) {
        const float4 v = *(const float4*)(xb + (size_t)c * NN);
        acc.x += fabsf(v.x); acc.y += fabsf(v.y);
        acc.z += fabsf(v.z); acc.w += fabsf(v.w);
    }
    *(float4*)(P + (size_t)(cy * BB + b) * NN + n0) = acc;
}

// ---------------------------------------------------------------------------
// Kernel 2: per-batch top-k selection -> 0/1 float mask.
// One block per batch, 256 threads, thread t owns contiguous tokens [16t,16t+16).
// Scores >= 0 so their fp32 bit patterns are order-isomorphic to uint32:
// greedy bit-build finds T = max u with count(s >= u) >= K  == kth largest.
// Tie-break matches jax.lax.top_k (lowest index first) via eq-prefix scan.
// All __syncthreads paths are block-uniform (count_ge result is broadcast).
// ---------------------------------------------------------------------------
__global__ __launch_bounds__(256) void select_kernel(
    const float* __restrict__ P, float* __restrict__ M) {
    const int b = blockIdx.x;
    const int t = threadIdx.x;
    __shared__ unsigned wsum[4];
    __shared__ unsigned bcast;
    __shared__ unsigned cnts[256];

    const float* p0 = P + (size_t)(0 * BB + b) * NN;
    const float* p1 = P + (size_t)(1 * BB + b) * NN;
    const float* p2 = P + (size_t)(2 * BB + b) * NN;
    const float* p3 = P + (size_t)(3 * BB + b) * NN;
    const int base = t * 16;

    unsigned su[16];
    #pragma unroll
    for (int j = 0; j < 16; j += 4) {
        float4 a0 = *(const float4*)(p0 + base + j);
        float4 a1 = *(const float4*)(p1 + base + j);
        float4 a2 = *(const float4*)(p2 + base + j);
        float4 a3 = *(const float4*)(p3 + base + j);
        su[j + 0] = __float_as_uint(a0.x + a1.x + a2.x + a3.x);
        su[j + 1] = __float_as_uint(a0.y + a1.y + a2.y + a3.y);
        su[j + 2] = __float_as_uint(a0.z + a1.z + a2.z + a3.z);
        su[j + 3] = __float_as_uint(a0.w + a1.w + a2.w + a3.w);
    }

    // count of scores (this batch) with bits >= thr, block-wide (uniform result)
    auto count_ge = [&](unsigned thr) -> unsigned {
        unsigned c = 0;
        #pragma unroll
        for (int j = 0; j < 16; ++j) c += (su[j] >= thr) ? 1u : 0u;
        #pragma unroll
        for (int off = 32; off; off >>= 1) c += __shfl_down(c, off, 64);
        const int wave = t >> 6;
        if ((t & 63) == 0) wsum[wave] = c;
        __syncthreads();
        if (t == 0) bcast = wsum[0] + wsum[1] + wsum[2] + wsum[3];
        __syncthreads();
        unsigned tot = bcast;
        __syncthreads();   // protect wsum/bcast before next call reuses them
        return tot;
    };

    unsigned T = 0;
    for (int bit = 31; bit >= 0; --bit) {
        unsigned cand = T | (1u << bit);
        if (count_ge(cand) >= KKEEP) T = cand;
    }
    const unsigned cnt_gt = count_ge(T + 1u);      // strictly greater
    const unsigned need_eq = KKEEP - cnt_gt;       // >=1 by maximality of T

    // exclusive prefix (in token order) of #equal-to-T per thread chunk
    unsigned local_eq = 0;
    #pragma unroll
    for (int j = 0; j < 16; ++j) local_eq += (su[j] == T) ? 1u : 0u;
    cnts[t] = local_eq;
    __syncthreads();
    unsigned prefix = 0;
    for (int p = 0; p < t; ++p) prefix += cnts[p];

    float* mb = M + (size_t)b * NN + base;
    unsigned run = prefix;
    #pragma unroll
    for (int j = 0; j < 16; ++j) {
        bool sel;
        if (su[j] > T)       sel = true;
        else if (su[j] == T) { sel = (run < need_eq); ++run; }
        else                 sel = false;
        mb[j] = sel ? 1.0f : 0.0f;
    }
}

// ---------------------------------------------------------------------------
// Kernel 3: out[b][c] = (1/2048) * sum_n mask[b][n] * x[b][c][n]
// One wave per (b,c) row; 4 waves/block; float4 loads (row = 16 KiB).
// Mask rows are reused 256x per batch -> L2/L3 hits.
// ---------------------------------------------------------------------------
__global__ __launch_bounds__(256) void pool_kernel(
    const float* __restrict__ x, const float* __restrict__ M,
    float* __restrict__ out) {
    const int wave = threadIdx.x >> 6;
    const int lane = threadIdx.x & 63;
    const int row  = blockIdx.x * 4 + wave;   // row = b*CC + c
    const int b    = row >> 8;
    const float* xr = x + (size_t)row * NN;
    const float* mr = M + (size_t)b * NN;
    float acc = 0.f;
    #pragma unroll
    for (int j = 0; j < 16; ++j) {
        const int n = j * 256 + lane * 4;
        const float4 v = *(const float4*)(xr + n);
        const float4 m = *(const float4*)(mr + n);
        acc += v.x * m.x + v.y * m.y + v.z * m.z + v.w * m.w;
    }
    #pragma unroll
    for (int off = 32; off; off >>= 1) acc += __shfl_down(acc, off, 64);
    if (lane == 0) out[row] = acc * (1.0f / 2048.0f);
}

extern "C" void kernel_launch(void* const* d_in, const int* in_sizes, int n_in,
                              void* d_out, int out_size, void* d_ws, size_t ws_size,
                              hipStream_t stream) {
    const float* x = (const float*)d_in[0];
    float* out = (float*)d_out;
    // ws layout: P = [4][64][4096] fp32 partial scores (4 MB), M = [64][4096]
    // fp32 mask (1 MB). Total 5 MB. Everything read is written first each call
    // (P fully covered by kernel 1, M fully covered by kernel 2), so the
    // harness's 0xAA re-poison of d_ws is harmless.
    float* P = (float*)d_ws;
    float* M = P + (size_t)4 * BB * NN;

    score_partial_kernel<<<dim3(BB * 4, 4), 256, 0, stream>>>(x, P);
    select_kernel<<<BB, 256, 0, stream>>>(P, M);
    pool_kernel<<<(BB * CC) / 4, 256, 0, stream>>>(x, M, out);
}